// Round 7
// baseline (197.707 us; speedup 1.0000x reference)
//
#include <hip/hip_runtime.h>
#include <stdint.h>

// Problem constants: B=32, N=512, F_IN=16, H=8, D_HID=8, D_OUT=32, ALPHA=0.2
// Inputs/outputs fp32. Intermediates in __device__ globals, fully rewritten
// each call (graph-safe). Sparsity: adjacency ~5% -> iterate set mask bits.
// Softmax without max-subtraction is exact here: unmasked scores are O(0.5),
// masked p == 0 exactly (matches reference exp(NEG - max) == 0).
//
// Round-7 changes:
//  - k_gat: preload the row's 8 mask words into registers BEFORE phase 0
//    (their ~400-900 cyc uncoalesced-load latency hides behind the GEMV +
//    barrier instead of sitting on the phase-1 critical path).
//  - k_qpart: 128 slices x 128 kk (partial traffic 16 MB -> 8 MB), unroll 8.
//  - k_qred: 128 slices, 128x128 grid.

typedef unsigned long long u64;

__device__ __forceinline__ float eluf(float x) { return x > 0.f ? x : __expf(x) - 1.f; }
__device__ __forceinline__ float lrelu(float x) { return fmaxf(x, 0.2f * x); }

// ---------------- module-owned intermediates ----------------
__device__ u64   g_mask[131072];     // [B][N][8]
__device__ float g_hcat[1048576];    // [B][N][64]
__device__ float g_Who[524288];      // [B][N][32]
__device__ float g_g1[16384];        // [B][N]
__device__ float g_g2[16384];        // [B][N]
__device__ float g_out2[524288];     // [B][N][32]
__device__ float g_partial[2097152]; // [128 k-slices][32 b][512 n'] (8 MB)

// ---------------- K0: pack (adj > 0) into bitmasks ----------------
__global__ __launch_bounds__(256) void k_mask(const float* __restrict__ adj) {
  int wid = blockIdx.x * 4 + (threadIdx.x >> 6);   // 8192 waves
  int lane = threadIdx.x & 63;
#pragma unroll
  for (int seg = 0; seg < 16; ++seg) {
    int gw = wid * 16 + seg;                       // < 131072 = B*N*8
    float v = adj[(size_t)(gw >> 3) * 512 + (gw & 7) * 64 + lane];
    u64 bal = __ballot(v > 0.f);
    if (lane == 0) g_mask[gw] = bal;
  }
}

// ---------------- K1: fused Wh/f1/f2 + GAT attention + aggregate + elu ----------------
// block = (b,h), 512 threads, thread = row i. Wh tile at stride 10 floats
// (40 B: 8-aligned, (10*col) mod 32 spreads float2 gathers ~4-way max).
__global__ __launch_bounds__(512) void k_gat(const float* __restrict__ xv,
                                             const float* __restrict__ whd,
                                             const float* __restrict__ a1,
                                             const float* __restrict__ a2) {
  __shared__ float w_s[128];
  __shared__ float a1s[8], a2s[8];
  __shared__ float wh_s[5120];    // [512 cols][10] (20 KB)
  __shared__ float f2s[512];

  int bh = blockIdx.x;            // b*8 + h
  int b = bh >> 3, h = bh & 7;
  int tid = threadIdx.x;          // row i

  // issue the row's mask words FIRST: one 64-B line per lane; latency hides
  // behind the phase-0 GEMV + barrier.
  const u64* mrow = g_mask + (size_t)b * 4096 + (size_t)tid * 8;
  u64 mreg[8];
#pragma unroll
  for (int w = 0; w < 8; ++w) mreg[w] = mrow[w];

  if (tid < 128) w_s[tid] = whd[h * 128 + tid];
  if (tid < 8) { a1s[tid] = a1[h * 8 + tid]; a2s[tid] = a2[h * 8 + tid]; }
  __syncthreads();

  // phase 0: own-row Wh, f1, f2
  const float4* xp = (const float4*)(xv + (size_t)(b * 512 + tid) * 16);
  float x[16];
#pragma unroll
  for (int i = 0; i < 4; ++i) {
    float4 v = xp[i];
    x[4 * i] = v.x; x[4 * i + 1] = v.y; x[4 * i + 2] = v.z; x[4 * i + 3] = v.w;
  }
  float wh[8] = {0, 0, 0, 0, 0, 0, 0, 0};
#pragma unroll
  for (int f = 0; f < 16; ++f) {
    float xf = x[f];
#pragma unroll
    for (int d = 0; d < 8; ++d) wh[d] += xf * w_s[f * 8 + d];
  }
  float f1v = 0.f, s2 = 0.f;
#pragma unroll
  for (int d = 0; d < 8; ++d) { f1v += wh[d] * a1s[d]; s2 += wh[d] * a2s[d]; }
  f2s[tid] = s2;
#pragma unroll
  for (int k = 0; k < 4; ++k)
    *(float2*)(wh_s + tid * 10 + 2 * k) = make_float2(wh[2 * k], wh[2 * k + 1]);
  __syncthreads();

  // phase 1: sparse attention over set bits (mask already in registers)
  float acc[8] = {0, 0, 0, 0, 0, 0, 0, 0};
  float sum = 0.f;
#pragma unroll
  for (int w = 0; w < 8; ++w) {
    u64 mq = mreg[w];
    while (mq) {
      int j = __builtin_ctzll(mq);
      mq &= mq - 1;
      int col = w * 64 + j;
      float p = __expf(lrelu(f1v + f2s[col]));
      sum += p;
      const float* wr = wh_s + col * 10;
      float2 A = *(const float2*)(wr);
      float2 Bv = *(const float2*)(wr + 2);
      float2 C = *(const float2*)(wr + 4);
      float2 D = *(const float2*)(wr + 6);
      acc[0] += p * A.x;  acc[1] += p * A.y;  acc[2] += p * Bv.x; acc[3] += p * Bv.y;
      acc[4] += p * C.x;  acc[5] += p * C.y;  acc[6] += p * D.x;  acc[7] += p * D.y;
    }
  }

  float rs = sum > 0.f ? 1.0f / sum : 0.f;
  float* dst = g_hcat + (size_t)(b * 512 + tid) * 64 + h * 8;
  *(float4*)dst = make_float4(eluf(acc[0] * rs), eluf(acc[1] * rs), eluf(acc[2] * rs), eluf(acc[3] * rs));
  *(float4*)(dst + 4) = make_float4(eluf(acc[4] * rs), eluf(acc[5] * rs), eluf(acc[6] * rs), eluf(acc[7] * rs));
}

// ---------------- K2: Who = hcat @ W_out, g1, g2 ----------------
__global__ __launch_bounds__(128) void k_who(const float* __restrict__ wout,
                                             const float* __restrict__ a1o,
                                             const float* __restrict__ a2o) {
  __shared__ float wo_s[2048];
  __shared__ float a1s[32], a2s[32];
  int tid = threadIdx.x;
  for (int i = tid; i < 2048; i += 128) wo_s[i] = wout[i];
  if (tid < 32) { a1s[tid] = a1o[tid]; a2s[tid] = a2o[tid]; }
  __syncthreads();

  int idx = blockIdx.x * 128 + tid;               // 32768 total
  int g = idx >> 1;                               // row: b*512 + n
  int db = (idx & 1) * 16;                        // d-range base

  const float4* hp = (const float4*)(g_hcat + (size_t)g * 64);
  float acc[16];
#pragma unroll
  for (int d = 0; d < 16; ++d) acc[d] = 0.f;
#pragma unroll
  for (int f4 = 0; f4 < 16; ++f4) {
    float4 h4 = hp[f4];
    float hv[4] = {h4.x, h4.y, h4.z, h4.w};
#pragma unroll
    for (int k = 0; k < 4; ++k) {
      const float* wr = wo_s + (f4 * 4 + k) * 32 + db;   // 2 addrs/wave: broadcast
      float hvk = hv[k];
#pragma unroll
      for (int d = 0; d < 16; ++d) acc[d] += hvk * wr[d];
    }
  }
  float s1 = 0.f, s2 = 0.f;
#pragma unroll
  for (int d = 0; d < 16; ++d) { s1 += acc[d] * a1s[db + d]; s2 += acc[d] * a2s[db + d]; }
  s1 += __shfl_xor(s1, 1);
  s2 += __shfl_xor(s2, 1);

  float* wdst = g_Who + (size_t)g * 32 + db;
#pragma unroll
  for (int d4 = 0; d4 < 4; ++d4)
    *(float4*)(wdst + d4 * 4) = make_float4(acc[d4 * 4], acc[d4 * 4 + 1], acc[d4 * 4 + 2], acc[d4 * 4 + 3]);
  if ((idx & 1) == 0) { g_g1[g] = s1; g_g2[g] = s2; }
}

// ---------------- K3: output attention + aggregate + elu -> out2 ----------------
__global__ __launch_bounds__(512) void k_att2() {
  __shared__ float pool[9216];    // union: Who chunk [256][36] | red [4][64][36]
  __shared__ float g2c[256];
  __shared__ u64 mask_s[512];

  int b = blockIdx.x >> 3;
  int t = blockIdx.x & 7;
  int tid = threadIdx.x;
  int w = tid >> 6;   // wave
  int l = tid & 63;   // lane = row

  mask_s[tid] = g_mask[(size_t)b * 4096 + t * 512 + tid];
  float g1v = g_g1[(size_t)b * 512 + t * 64 + l];

  float acc[32];
#pragma unroll
  for (int d = 0; d < 32; ++d) acc[d] = 0.f;
  float sum = 0.f;

#pragma unroll 1
  for (int c = 0; c < 2; ++c) {
    __syncthreads();
    {
      const float4* src = (const float4*)g_Who + (size_t)b * 4096;
      for (int i = tid; i < 2048; i += 512) {
        int m = i >> 3, d4 = i & 7;
        *(float4*)(pool + m * 36 + d4 * 4) = src[c * 2048 + i];
      }
      if (tid < 64) ((float4*)g2c)[tid] = ((const float4*)g_g2)[(size_t)b * 128 + c * 64 + tid];
    }
    __syncthreads();
    u64 mq = mask_s[l * 8 + c * 4 + (w >> 1)];
    uint32_t bits = (w & 1) ? (uint32_t)(mq >> 32) : (uint32_t)mq;
    while (bits) {
      int j = __builtin_ctz(bits);
      bits &= bits - 1;
      float p = __expf(lrelu(g1v + g2c[w * 32 + j]));
      sum += p;
      const float* wq = pool + (w * 32 + j) * 36;
#pragma unroll
      for (int d4 = 0; d4 < 8; ++d4) {
        float4 v = *(const float4*)(wq + d4 * 4);
        acc[d4 * 4]     += p * v.x;
        acc[d4 * 4 + 1] += p * v.y;
        acc[d4 * 4 + 2] += p * v.z;
        acc[d4 * 4 + 3] += p * v.w;
      }
    }
  }

  // tree-reduce (acc,sum) across 8 waves; pool chunk data dead, reuse
#pragma unroll 1
  for (int step = 4; step >= 1; step >>= 1) {
    __syncthreads();
    if (w >= step && w < 2 * step) {
      float* rp = pool + (size_t)((w - step) * 64 + l) * 36;
#pragma unroll
      for (int d4 = 0; d4 < 8; ++d4)
        *(float4*)(rp + d4 * 4) = make_float4(acc[d4 * 4], acc[d4 * 4 + 1], acc[d4 * 4 + 2], acc[d4 * 4 + 3]);
      rp[32] = sum;
    }
    __syncthreads();
    if (w < step) {
      const float* rp = pool + (size_t)(w * 64 + l) * 36;
#pragma unroll
      for (int d = 0; d < 32; ++d) acc[d] += rp[d];
      sum += rp[32];
    }
  }

  if (w == 0) {
    float rs = sum > 0.f ? 1.0f / sum : 0.f;
    float* dst = g_out2 + (size_t)(b * 512 + t * 64 + l) * 32;
#pragma unroll
    for (int d4 = 0; d4 < 8; ++d4)
      *(float4*)(dst + d4 * 4) = make_float4(eluf(acc[d4 * 4] * rs), eluf(acc[d4 * 4 + 1] * rs),
                                             eluf(acc[d4 * 4 + 2] * rs), eluf(acc[d4 * 4 + 3] * rs));
  }
}

// ---------------- K4: q partials ----------------
// block: s-slice (128 k) x n'-chunk c (256 n'); 4 waves = 4 b-groups (8 b each).
// Lane = 4 consecutive n' (float4 W_q loads, 1 KB/wave/iter). out2 slice in LDS
// at stride 36 ([kk][32 b]): b128-aligned, uniform-broadcast reads.
__global__ __launch_bounds__(256) void k_qpart(const float* __restrict__ Wq) {
  __shared__ float outS[128 * 36];                // 18 KB
  int s = blockIdx.x >> 1;                        // k-slice, 128 slices of 128
  int c = blockIdx.x & 1;                         // n'-chunk of 256
  int tid = threadIdx.x;
  int lane = tid & 63;
  int bg = tid >> 6;                              // wave = 8-b group

  // stage out2[32 b][128 kk] -> outS[kk*36 + b]
  for (int i = tid; i < 1024; i += 256) {         // 1024 float4 = 4096 floats
    int bb = i >> 5, kk4 = (i & 31) * 4;
    float4 v = *(const float4*)(g_out2 + (size_t)bb * 16384 + s * 128 + kk4);
    outS[(kk4 + 0) * 36 + bb] = v.x;
    outS[(kk4 + 1) * 36 + bb] = v.y;
    outS[(kk4 + 2) * 36 + bb] = v.z;
    outS[(kk4 + 3) * 36 + bb] = v.w;
  }
  __syncthreads();

  const float* wp = Wq + (size_t)(s * 128) * 512 + c * 256 + lane * 4;
  float4 acc[8];
#pragma unroll
  for (int j = 0; j < 8; ++j) acc[j] = make_float4(0.f, 0.f, 0.f, 0.f);

#pragma unroll 8
  for (int kk = 0; kk < 128; ++kk) {
    float4 wv = *(const float4*)(wp + (size_t)kk * 512);   // coalesced 1 KB/wave
    const float* ob = outS + kk * 36 + bg * 8;             // uniform -> broadcast
    float4 o1 = *(const float4*)(ob);
    float4 o2 = *(const float4*)(ob + 4);
    float ov[8] = {o1.x, o1.y, o1.z, o1.w, o2.x, o2.y, o2.z, o2.w};
#pragma unroll
    for (int j = 0; j < 8; ++j) {
      acc[j].x += ov[j] * wv.x; acc[j].y += ov[j] * wv.y;
      acc[j].z += ov[j] * wv.z; acc[j].w += ov[j] * wv.w;
    }
  }
#pragma unroll
  for (int j = 0; j < 8; ++j)
    *(float4*)(g_partial + (size_t)(s * 32 + bg * 8 + j) * 512 + c * 256 + lane * 4) = acc[j];
}

// ---------------- K5: reduce 128 partial slices + b_q -> fp32 out [B][N] ----------------
__global__ __launch_bounds__(128) void k_qred(const float* __restrict__ bq,
                                              float* __restrict__ out) {
  int g = blockIdx.x * 128 + threadIdx.x;         // b*512 + n'
  int b = g >> 9, np = g & 511;
  float q = bq[np];
#pragma unroll 8
  for (int s = 0; s < 128; ++s) q += g_partial[(size_t)(s * 32 + b) * 512 + np];
  out[g] = q;
}

extern "C" void kernel_launch(void* const* d_in, const int* in_sizes, int n_in,
                              void* d_out, int out_size, void* d_ws, size_t ws_size,
                              hipStream_t stream) {
  const float* xv = (const float*)d_in[0];
  const float* adj = (const float*)d_in[1];
  const float* W_heads = (const float*)d_in[2];
  const float* a1 = (const float*)d_in[3];
  const float* a2 = (const float*)d_in[4];
  const float* W_out = (const float*)d_in[5];
  const float* a1_out = (const float*)d_in[6];
  const float* a2_out = (const float*)d_in[7];
  const float* W_q = (const float*)d_in[8];
  const float* b_q = (const float*)d_in[9];

  k_mask<<<2048, 256, 0, stream>>>(adj);
  k_gat<<<256, 512, 0, stream>>>(xv, W_heads, a1, a2);
  k_who<<<256, 128, 0, stream>>>(W_out, a1_out, a2_out);
  k_att2<<<256, 512, 0, stream>>>();
  k_qpart<<<256, 256, 0, stream>>>(W_q);
  k_qred<<<128, 128, 0, stream>>>(b_q, (float*)d_out);
}

// Round 8
// 164.393 us; speedup vs baseline: 1.2026x; 1.2026x over previous
//
#include <hip/hip_runtime.h>
#include <stdint.h>

// Problem constants: B=32, N=512, F_IN=16, H=8, D_HID=8, D_OUT=32, ALPHA=0.2
// Inputs/outputs fp32. Intermediates in __device__ globals, fully rewritten
// each call (graph-safe). Sparsity: adjacency ~5% -> iterate set mask bits.
// Softmax without max-subtraction is exact here: unmasked scores are O(0.5),
// masked p == 0 exactly (matches reference exp(NEG - max) == 0).
//
// Round-8 changes:
//  - k_qpart: back to high concurrency (512 blocks x 512 threads = 16 waves/CU,
//    8 b-groups share the block's W_q slice via L1). Round-7's 1-block/CU shape
//    was latency-bound at 630 GB/s.
//  - k_gat: Wh tile as two float4 arrays -> 2x ds_read_b128 per nnz instead of
//    4x ds_read_b64 (fewer LDS issues; b128 start-bank is 8-way max regardless).
//  - k_qred: split-K form (4 waves x 64 slices each, LDS reduce).

typedef unsigned long long u64;

__device__ __forceinline__ float eluf(float x) { return x > 0.f ? x : __expf(x) - 1.f; }
__device__ __forceinline__ float lrelu(float x) { return fmaxf(x, 0.2f * x); }

// ---------------- module-owned intermediates ----------------
__device__ u64   g_mask[131072];     // [B][N][8]
__device__ float g_hcat[1048576];    // [B][N][64]
__device__ float g_Who[524288];      // [B][N][32]
__device__ float g_g1[16384];        // [B][N]
__device__ float g_g2[16384];        // [B][N]
__device__ float g_out2[524288];     // [B][N][32]
__device__ float g_partial[4194304]; // [256 k-slices][32 b][512 n'] (16 MB)

// ---------------- K0: pack (adj > 0) into bitmasks ----------------
__global__ __launch_bounds__(256) void k_mask(const float* __restrict__ adj) {
  int wid = blockIdx.x * 4 + (threadIdx.x >> 6);   // 8192 waves
  int lane = threadIdx.x & 63;
#pragma unroll
  for (int seg = 0; seg < 16; ++seg) {
    int gw = wid * 16 + seg;                       // < 131072 = B*N*8
    float v = adj[(size_t)(gw >> 3) * 512 + (gw & 7) * 64 + lane];
    u64 bal = __ballot(v > 0.f);
    if (lane == 0) g_mask[gw] = bal;
  }
}

// ---------------- K1: fused Wh/f1/f2 + GAT attention + aggregate + elu ----------------
// block = (b,h), 512 threads, thread = row i. Wh tile in two float4 arrays:
// per nnz gather = 2x ds_read_b128 + 1x ds_read_b32 (f2).
__global__ __launch_bounds__(512) void k_gat(const float* __restrict__ xv,
                                             const float* __restrict__ whd,
                                             const float* __restrict__ a1,
                                             const float* __restrict__ a2) {
  __shared__ float w_s[128];
  __shared__ float a1s[8], a2s[8];
  __shared__ float wh_lo[2048];   // [512 cols][4] (8 KB)
  __shared__ float wh_hi[2048];   // [512 cols][4] (8 KB)
  __shared__ float f2s[512];

  int bh = blockIdx.x;            // b*8 + h
  int b = bh >> 3, h = bh & 7;
  int tid = threadIdx.x;          // row i

  // issue the row's mask words FIRST (one 64-B line/lane); latency hides
  // behind the phase-0 GEMV + barrier.
  const u64* mrow = g_mask + (size_t)b * 4096 + (size_t)tid * 8;
  u64 mreg[8];
#pragma unroll
  for (int w = 0; w < 8; ++w) mreg[w] = mrow[w];

  if (tid < 128) w_s[tid] = whd[h * 128 + tid];
  if (tid < 8) { a1s[tid] = a1[h * 8 + tid]; a2s[tid] = a2[h * 8 + tid]; }
  __syncthreads();

  // phase 0: own-row Wh, f1, f2
  const float4* xp = (const float4*)(xv + (size_t)(b * 512 + tid) * 16);
  float x[16];
#pragma unroll
  for (int i = 0; i < 4; ++i) {
    float4 v = xp[i];
    x[4 * i] = v.x; x[4 * i + 1] = v.y; x[4 * i + 2] = v.z; x[4 * i + 3] = v.w;
  }
  float wh[8] = {0, 0, 0, 0, 0, 0, 0, 0};
#pragma unroll
  for (int f = 0; f < 16; ++f) {
    float xf = x[f];
#pragma unroll
    for (int d = 0; d < 8; ++d) wh[d] += xf * w_s[f * 8 + d];
  }
  float f1v = 0.f, s2 = 0.f;
#pragma unroll
  for (int d = 0; d < 8; ++d) { f1v += wh[d] * a1s[d]; s2 += wh[d] * a2s[d]; }
  f2s[tid] = s2;
  *(float4*)(wh_lo + tid * 4) = make_float4(wh[0], wh[1], wh[2], wh[3]);
  *(float4*)(wh_hi + tid * 4) = make_float4(wh[4], wh[5], wh[6], wh[7]);
  __syncthreads();

  // phase 1: sparse attention over set bits (mask in registers)
  float acc[8] = {0, 0, 0, 0, 0, 0, 0, 0};
  float sum = 0.f;
#pragma unroll
  for (int w = 0; w < 8; ++w) {
    u64 mq = mreg[w];
    while (mq) {
      int j = __builtin_ctzll(mq);
      mq &= mq - 1;
      int col = w * 64 + j;
      float p = __expf(lrelu(f1v + f2s[col]));
      sum += p;
      float4 A = *(const float4*)(wh_lo + col * 4);
      float4 Bv = *(const float4*)(wh_hi + col * 4);
      acc[0] += p * A.x;  acc[1] += p * A.y;  acc[2] += p * A.z;  acc[3] += p * A.w;
      acc[4] += p * Bv.x; acc[5] += p * Bv.y; acc[6] += p * Bv.z; acc[7] += p * Bv.w;
    }
  }

  float rs = sum > 0.f ? 1.0f / sum : 0.f;
  float* dst = g_hcat + (size_t)(b * 512 + tid) * 64 + h * 8;
  *(float4*)dst = make_float4(eluf(acc[0] * rs), eluf(acc[1] * rs), eluf(acc[2] * rs), eluf(acc[3] * rs));
  *(float4*)(dst + 4) = make_float4(eluf(acc[4] * rs), eluf(acc[5] * rs), eluf(acc[6] * rs), eluf(acc[7] * rs));
}

// ---------------- K2: Who = hcat @ W_out, g1, g2 ----------------
__global__ __launch_bounds__(128) void k_who(const float* __restrict__ wout,
                                             const float* __restrict__ a1o,
                                             const float* __restrict__ a2o) {
  __shared__ float wo_s[2048];
  __shared__ float a1s[32], a2s[32];
  int tid = threadIdx.x;
  for (int i = tid; i < 2048; i += 128) wo_s[i] = wout[i];
  if (tid < 32) { a1s[tid] = a1o[tid]; a2s[tid] = a2o[tid]; }
  __syncthreads();

  int idx = blockIdx.x * 128 + tid;               // 32768 total
  int g = idx >> 1;                               // row: b*512 + n
  int db = (idx & 1) * 16;                        // d-range base

  const float4* hp = (const float4*)(g_hcat + (size_t)g * 64);
  float acc[16];
#pragma unroll
  for (int d = 0; d < 16; ++d) acc[d] = 0.f;
#pragma unroll
  for (int f4 = 0; f4 < 16; ++f4) {
    float4 h4 = hp[f4];
    float hv[4] = {h4.x, h4.y, h4.z, h4.w};
#pragma unroll
    for (int k = 0; k < 4; ++k) {
      const float* wr = wo_s + (f4 * 4 + k) * 32 + db;   // 2 addrs/wave: broadcast
      float hvk = hv[k];
#pragma unroll
      for (int d = 0; d < 16; ++d) acc[d] += hvk * wr[d];
    }
  }
  float s1 = 0.f, s2 = 0.f;
#pragma unroll
  for (int d = 0; d < 16; ++d) { s1 += acc[d] * a1s[db + d]; s2 += acc[d] * a2s[db + d]; }
  s1 += __shfl_xor(s1, 1);
  s2 += __shfl_xor(s2, 1);

  float* wdst = g_Who + (size_t)g * 32 + db;
#pragma unroll
  for (int d4 = 0; d4 < 4; ++d4)
    *(float4*)(wdst + d4 * 4) = make_float4(acc[d4 * 4], acc[d4 * 4 + 1], acc[d4 * 4 + 2], acc[d4 * 4 + 3]);
  if ((idx & 1) == 0) { g_g1[g] = s1; g_g2[g] = s2; }
}

// ---------------- K3: output attention + aggregate + elu -> out2 ----------------
__global__ __launch_bounds__(512) void k_att2() {
  __shared__ float pool[9216];    // union: Who chunk [256][36] | red [4][64][36]
  __shared__ float g2c[256];
  __shared__ u64 mask_s[512];

  int b = blockIdx.x >> 3;
  int t = blockIdx.x & 7;
  int tid = threadIdx.x;
  int w = tid >> 6;   // wave
  int l = tid & 63;   // lane = row

  mask_s[tid] = g_mask[(size_t)b * 4096 + t * 512 + tid];
  float g1v = g_g1[(size_t)b * 512 + t * 64 + l];

  float acc[32];
#pragma unroll
  for (int d = 0; d < 32; ++d) acc[d] = 0.f;
  float sum = 0.f;

#pragma unroll 1
  for (int c = 0; c < 2; ++c) {
    __syncthreads();
    {
      const float4* src = (const float4*)g_Who + (size_t)b * 4096;
      for (int i = tid; i < 2048; i += 512) {
        int m = i >> 3, d4 = i & 7;
        *(float4*)(pool + m * 36 + d4 * 4) = src[c * 2048 + i];
      }
      if (tid < 64) ((float4*)g2c)[tid] = ((const float4*)g_g2)[(size_t)b * 128 + c * 64 + tid];
    }
    __syncthreads();
    u64 mq = mask_s[l * 8 + c * 4 + (w >> 1)];
    uint32_t bits = (w & 1) ? (uint32_t)(mq >> 32) : (uint32_t)mq;
    while (bits) {
      int j = __builtin_ctz(bits);
      bits &= bits - 1;
      float p = __expf(lrelu(g1v + g2c[w * 32 + j]));
      sum += p;
      const float* wq = pool + (w * 32 + j) * 36;
#pragma unroll
      for (int d4 = 0; d4 < 8; ++d4) {
        float4 v = *(const float4*)(wq + d4 * 4);
        acc[d4 * 4]     += p * v.x;
        acc[d4 * 4 + 1] += p * v.y;
        acc[d4 * 4 + 2] += p * v.z;
        acc[d4 * 4 + 3] += p * v.w;
      }
    }
  }

  // tree-reduce (acc,sum) across 8 waves; pool chunk data dead, reuse
#pragma unroll 1
  for (int step = 4; step >= 1; step >>= 1) {
    __syncthreads();
    if (w >= step && w < 2 * step) {
      float* rp = pool + (size_t)((w - step) * 64 + l) * 36;
#pragma unroll
      for (int d4 = 0; d4 < 8; ++d4)
        *(float4*)(rp + d4 * 4) = make_float4(acc[d4 * 4], acc[d4 * 4 + 1], acc[d4 * 4 + 2], acc[d4 * 4 + 3]);
      rp[32] = sum;
    }
    __syncthreads();
    if (w < step) {
      const float* rp = pool + (size_t)(w * 64 + l) * 36;
#pragma unroll
      for (int d = 0; d < 32; ++d) acc[d] += rp[d];
      sum += rp[32];
    }
  }

  if (w == 0) {
    float rs = sum > 0.f ? 1.0f / sum : 0.f;
    float* dst = g_out2 + (size_t)(b * 512 + t * 64 + l) * 32;
#pragma unroll
    for (int d4 = 0; d4 < 8; ++d4)
      *(float4*)(dst + d4 * 4) = make_float4(eluf(acc[d4 * 4] * rs), eluf(acc[d4 * 4 + 1] * rs),
                                             eluf(acc[d4 * 4 + 2] * rs), eluf(acc[d4 * 4 + 3] * rs));
  }
}

// ---------------- K4: q partials ----------------
// block: s-slice (64 k) x n'-chunk c (256 n'); 512 threads = 8 waves = 8
// b-groups (4 b each). Lane = 4 consecutive n' (float4 W_q loads). All 8 waves
// share the block's 64-KB W_q slice via L1. out2 slice in LDS at stride 36.
__global__ __launch_bounds__(512) void k_qpart(const float* __restrict__ Wq) {
  __shared__ float outS[64 * 36];                 // 9.2 KB
  int s = blockIdx.x >> 1;                        // k-slice, 256 slices of 64
  int c = blockIdx.x & 1;                         // n'-chunk of 256
  int tid = threadIdx.x;
  int lane = tid & 63;
  int bg = tid >> 6;                              // wave = 4-b group (0..7)

  // stage out2[32 b][64 kk] -> outS[kk*36 + b]
  if (tid < 512) {
    int i = tid;                                  // 512 float4 = 2048 floats
    int bb = i >> 4, kk4 = (i & 15) * 4;
    float4 v = *(const float4*)(g_out2 + (size_t)bb * 16384 + s * 64 + kk4);
    outS[(kk4 + 0) * 36 + bb] = v.x;
    outS[(kk4 + 1) * 36 + bb] = v.y;
    outS[(kk4 + 2) * 36 + bb] = v.z;
    outS[(kk4 + 3) * 36 + bb] = v.w;
  }
  __syncthreads();

  const float* wp = Wq + (size_t)(s * 64) * 512 + c * 256 + lane * 4;
  float4 acc[4];
#pragma unroll
  for (int j = 0; j < 4; ++j) acc[j] = make_float4(0.f, 0.f, 0.f, 0.f);

#pragma unroll 8
  for (int kk = 0; kk < 64; ++kk) {
    float4 wv = *(const float4*)(wp + (size_t)kk * 512);   // coalesced 1 KB/wave
    const float* ob = outS + kk * 36 + bg * 4;             // uniform -> broadcast
    float4 o = *(const float4*)(ob);
    float ov[4] = {o.x, o.y, o.z, o.w};
#pragma unroll
    for (int j = 0; j < 4; ++j) {
      acc[j].x += ov[j] * wv.x; acc[j].y += ov[j] * wv.y;
      acc[j].z += ov[j] * wv.z; acc[j].w += ov[j] * wv.w;
    }
  }
#pragma unroll
  for (int j = 0; j < 4; ++j)
    *(float4*)(g_partial + (size_t)(s * 32 + bg * 4 + j) * 512 + c * 256 + lane * 4) = acc[j];
}

// ---------------- K5: reduce 256 partial slices + b_q -> fp32 out [B][N] ----------------
// block = 64 outputs x 4 split-K waves; LDS reduce. grid 256.
__global__ __launch_bounds__(256) void k_qred(const float* __restrict__ bq,
                                              float* __restrict__ out) {
  __shared__ float red[4][64];
  int tid = threadIdx.x;
  int w = tid >> 6, lane = tid & 63;
  int g = blockIdx.x * 64 + lane;                 // b*512 + n'
  int b = g >> 9, np = g & 511;

  float q = 0.f;
#pragma unroll 8
  for (int i = 0; i < 64; ++i) {
    int s = w + i * 4;                            // covers 256 slices across 4 waves
    q += g_partial[(size_t)(s * 32 + b) * 512 + np];
  }
  red[w][lane] = q;
  __syncthreads();
  if (w == 0)
    out[g] = bq[np] + red[0][lane] + red[1][lane] + red[2][lane] + red[3][lane];
}

extern "C" void kernel_launch(void* const* d_in, const int* in_sizes, int n_in,
                              void* d_out, int out_size, void* d_ws, size_t ws_size,
                              hipStream_t stream) {
  const float* xv = (const float*)d_in[0];
  const float* adj = (const float*)d_in[1];
  const float* W_heads = (const float*)d_in[2];
  const float* a1 = (const float*)d_in[3];
  const float* a2 = (const float*)d_in[4];
  const float* W_out = (const float*)d_in[5];
  const float* a1_out = (const float*)d_in[6];
  const float* a2_out = (const float*)d_in[7];
  const float* W_q = (const float*)d_in[8];
  const float* b_q = (const float*)d_in[9];

  k_mask<<<2048, 256, 0, stream>>>(adj);
  k_gat<<<256, 512, 0, stream>>>(xv, W_heads, a1, a2);
  k_who<<<256, 128, 0, stream>>>(W_out, a1_out, a2_out);
  k_att2<<<256, 512, 0, stream>>>();
  k_qpart<<<512, 512, 0, stream>>>(W_q);
  k_qred<<<256, 256, 0, stream>>>(b_q, (float*)d_out);
}